// Round 7
// baseline (273.402 us; speedup 1.0000x reference)
//
#include <hip/hip_runtime.h>

// SGCN fused, MFMA v4: TB=8, 4 blocks/CU (grid=1024), f16 swizzled a_t (b128 frag reads),
// single g buffer (2 barriers/it), cross-it x prefetch, shfl-based s, setprio on GEMM-B.
// out[n,f,t,w] = sum_c W[c,f]*g[c,w] + b[f]*s[w],  g[c,w] = sum_v x[n,c,t,v]*a[n,t,v,w]
// x[128,256,64,32] f32, a[128,64,32,32] f32, W[256,256] f32, b[256] f32
// d_out = out (67,108,864 f32) ++ a (8,388,608 f32);  d_ws = Wt f16 [f][c] (131072 B)

#define NN 128
#define CC 256
#define TT 64
#define VV 32
#define FF 256
#define TB 8

typedef _Float16 half8 __attribute__((ext_vector_type(8)));
typedef _Float16 half4 __attribute__((ext_vector_type(4)));
typedef float floatx4 __attribute__((ext_vector_type(4)));

__global__ __launch_bounds__(256) void wt_prep_kernel(const float* __restrict__ W,
                                                      _Float16* __restrict__ Wt) {
    const int c = blockIdx.x;
    const int f = threadIdx.x;
    Wt[f * CC + c] = (_Float16)W[c * FF + f];
}

__global__ __launch_bounds__(256, 4) void sgcn_mfma4_kernel(
    const float* __restrict__ x, const float* __restrict__ a,
    const _Float16* __restrict__ Wt, const float* __restrict__ b,
    float* __restrict__ out, float* __restrict__ out_a)
{
    // a_t: rows (it,w) of 32 f16 v-values, 64B/row, swizzle byte ^= (row&3)<<4
    __shared__ _Float16 a_t[TB * VV * VV];      // 16 KB
    // g: rows w of 256 f16 c-values, 512B/row, swizzle byte ^= (row&7)<<4
    __shared__ _Float16 g_s[VV * 256];          // 16 KB
    __shared__ float    s_part[TB][4][VV];      // 4 KB (per-wave partial col sums)
    __shared__ float    s_lds[TB][VV];          // 1 KB
    // total 37.9 KB -> 4 blocks/CU

    const int tid  = threadIdx.x;
    const int lane = tid & 63;
    const int wv   = tid >> 6;       // wave 0..3
    const int l15  = lane & 15;
    const int lg   = lane >> 4;      // 0..3
    const int blk  = blockIdx.x;
    const int n    = blk >> 3;       // TT/TB = 8 t-groups per n
    const int t0   = (blk & 7) * TB;

    char* at_base = (char*)a_t;
    char* g_base  = (char*)g_s;

    // ---- x loads for it=0, issued first (in flight under all of phase 0)
    float4 xf[8];
    #pragma unroll
    for (int ci = 0; ci < 4; ++ci) {
        const int c = (wv * 4 + ci) * 16 + l15;
        const float* xp = x + (((size_t)n * CC + c) * TT + t0) * VV + 8 * lg;
        xf[ci * 2 + 0] = *reinterpret_cast<const float4*>(xp);
        xf[ci * 2 + 1] = *reinterpret_cast<const float4*>(xp + 4);
    }

    // ---- phase 0: load a (TB t's), mirror, stage transposed f16, shfl partial sums
    {
        const int v  = tid >> 3;          // 0..31
        const int w0 = (tid & 7) * 4;     // 0,4,...,28
        #pragma unroll
        for (int it = 0; it < TB; ++it) {
            const size_t off = ((size_t)(n * TT + t0 + it)) * (VV * VV) + tid * 4;
            float4 av = *reinterpret_cast<const float4*>(a + off);
            *reinterpret_cast<float4*>(out_a + off) = av;
            // transpose-write 4 f16 scalars: a_t[row=(it,w0+j)][v]
            #pragma unroll
            for (int j = 0; j < 4; ++j) {
                const int row = it * VV + w0 + j;
                const float e = j == 0 ? av.x : j == 1 ? av.y : j == 2 ? av.z : av.w;
                *reinterpret_cast<_Float16*>(at_base + row * 64 +
                                             ((v * 2) ^ ((row & 3) << 4))) = (_Float16)e;
            }
            // partial column sums over this wave's 8 v's (lanes stride-8 share w0)
            float4 p = av;
            #pragma unroll
            for (int m = 8; m <= 32; m <<= 1) {
                p.x += __shfl_xor(p.x, m);
                p.y += __shfl_xor(p.y, m);
                p.z += __shfl_xor(p.z, m);
                p.w += __shfl_xor(p.w, m);
            }
            if ((lane >> 3) == 0)   // lanes 0..7 hold the wave's partial for w0..w0+3
                *reinterpret_cast<float4*>(&s_part[it][wv][w0]) = p;
        }
    }

    float bv[4];
    #pragma unroll
    for (int fi = 0; fi < 4; ++fi) bv[fi] = b[16 * (wv * 4 + fi) + l15];

    __syncthreads();                  // a_t + s_part ready

    // ---- final s: 256 threads = (it, w)
    {
        const int it = tid >> 5, w = tid & 31;
        s_lds[it][w] = s_part[it][0][w] + s_part[it][1][w] +
                       s_part[it][2][w] + s_part[it][3][w];
    }

    #pragma unroll
    for (int it = 0; it < TB; ++it) {
        // ---- B-frags of a: one b128 each (swizzled rows)
        const int r0 = it * VV + l15, r1 = r0 + 16;
        half8 bA0 = *reinterpret_cast<const half8*>(at_base + r0 * 64 +
                                                    ((16 * lg) ^ ((r0 & 3) << 4)));
        half8 bA1 = *reinterpret_cast<const half8*>(at_base + r1 * 64 +
                                                    ((16 * lg) ^ ((r1 & 3) << 4)));

        // ---- convert prefetched x -> A-frags (frees xf for next prefetch)
        half8 af[4];
        #pragma unroll
        for (int ci = 0; ci < 4; ++ci) {
            float4 x0 = xf[ci * 2 + 0], x1 = xf[ci * 2 + 1];
            af[ci][0] = (_Float16)x0.x; af[ci][1] = (_Float16)x0.y;
            af[ci][2] = (_Float16)x0.z; af[ci][3] = (_Float16)x0.w;
            af[ci][4] = (_Float16)x1.x; af[ci][5] = (_Float16)x1.y;
            af[ci][6] = (_Float16)x1.z; af[ci][7] = (_Float16)x1.w;
        }

        // ---- prefetch x for it+1 (in flight across GEMM-A, barrier, GEMM-B)
        if (it + 1 < TB) {
            #pragma unroll
            for (int ci = 0; ci < 4; ++ci) {
                const int c = (wv * 4 + ci) * 16 + l15;
                const float* xp = x + (((size_t)n * CC + c) * TT + (t0 + it + 1)) * VV + 8 * lg;
                xf[ci * 2 + 0] = *reinterpret_cast<const float4*>(xp);
                xf[ci * 2 + 1] = *reinterpret_cast<const float4*>(xp + 4);
            }
        }

        // ---- GEMM-A: g[c,w]; write g^T rows, XOR swizzle
        #pragma unroll
        for (int ci = 0; ci < 4; ++ci) {
            const int ct = wv * 4 + ci;
            #pragma unroll
            for (int wt = 0; wt < 2; ++wt) {
                floatx4 acc = {0.f, 0.f, 0.f, 0.f};
                acc = __builtin_amdgcn_mfma_f32_16x16x32_f16(af[ci], wt ? bA1 : bA0, acc, 0, 0, 0);
                half4 gh;
                gh[0] = (_Float16)acc[0]; gh[1] = (_Float16)acc[1];
                gh[2] = (_Float16)acc[2]; gh[3] = (_Float16)acc[3];
                const int row = 16 * wt + l15;
                const int cb  = (ct * 16 + 4 * lg) * 2;
                *reinterpret_cast<half4*>(g_base + row * 512 + (cb ^ ((row & 7) << 4))) = gh;
            }
        }
        __syncthreads();              // g ready (it=0: s_lds also ordered)

        // ---- GEMM-B: D[w,f] = g^T · Wt (Wt streamed from L2)
        floatx4 acc2[8];
        #pragma unroll
        for (int q = 0; q < 8; ++q) acc2[q] = (floatx4){0.f, 0.f, 0.f, 0.f};

        __builtin_amdgcn_s_setprio(1);
        #pragma unroll
        for (int ks = 0; ks < 8; ++ks) {
            const int cb = (32 * ks + 8 * lg) * 2;
            half8 ga0 = *reinterpret_cast<const half8*>(g_base + l15 * 512 +
                                                        (cb ^ ((l15 & 7) << 4)));
            half8 ga1 = *reinterpret_cast<const half8*>(g_base + (16 + l15) * 512 +
                                                        (cb ^ (((16 + l15) & 7) << 4)));
            #pragma unroll
            for (int fi = 0; fi < 4; ++fi) {
                const int f = 16 * (wv * 4 + fi) + l15;
                half8 wb = *reinterpret_cast<const half8*>(Wt + (size_t)f * CC + 32 * ks + 8 * lg);
                acc2[fi * 2 + 0] = __builtin_amdgcn_mfma_f32_16x16x32_f16(ga0, wb, acc2[fi * 2 + 0], 0, 0, 0);
                acc2[fi * 2 + 1] = __builtin_amdgcn_mfma_f32_16x16x32_f16(ga1, wb, acc2[fi * 2 + 1], 0, 0, 0);
            }
        }
        __builtin_amdgcn_s_setprio(0);

        // ---- epilogue: out[n,f,t,w0..3] = acc + b[f]*s[w]
        #pragma unroll
        for (int fi = 0; fi < 4; ++fi) {
            const int f = 16 * (wv * 4 + fi) + l15;
            float* ob = out + (((size_t)n * FF + f) * TT + (t0 + it)) * VV;
            #pragma unroll
            for (int mt = 0; mt < 2; ++mt) {
                const int w0 = 16 * mt + 4 * lg;
                float4 sv = *reinterpret_cast<const float4*>(&s_lds[it][w0]);
                float4 o;
                o.x = acc2[fi * 2 + mt][0] + bv[fi] * sv.x;
                o.y = acc2[fi * 2 + mt][1] + bv[fi] * sv.y;
                o.z = acc2[fi * 2 + mt][2] + bv[fi] * sv.z;
                o.w = acc2[fi * 2 + mt][3] + bv[fi] * sv.w;
                *reinterpret_cast<float4*>(ob + w0) = o;
            }
        }
        if (it + 1 < TB) __syncthreads();   // g consumed; safe to overwrite
    }
}

// ---- fallback (verified round-3 scalar kernel): used only if ws too small
__global__ __launch_bounds__(256) void sgcn_fused_kernel(
    const float* __restrict__ x, const float* __restrict__ a,
    const float* __restrict__ W, const float* __restrict__ b,
    float* __restrict__ out, float* __restrict__ out_a)
{
    __shared__ float x_lds[CC][VV];
    __shared__ float a_lds[VV][VV];
    const int tid = threadIdx.x;
    const int nt  = blockIdx.x;
    const int n   = nt >> 6;
    const int t   = nt & 63;
    const float* xb = x + (size_t)n * CC * TT * VV + (size_t)t * VV;
    #pragma unroll
    for (int k = 0; k < 8; ++k) {
        int e = tid * 4 + k * 1024;
        int c = e >> 5, v = e & 31;
        float4 val = *reinterpret_cast<const float4*>(xb + (size_t)c * (TT * VV) + v);
        *reinterpret_cast<float4*>(&x_lds[c][v]) = val;
    }
    {
        const float* ab = a + (size_t)nt * (VV * VV);
        float4 av = *reinterpret_cast<const float4*>(ab + tid * 4);
        *reinterpret_cast<float4*>(&a_lds[0][0] + tid * 4) = av;
        *reinterpret_cast<float4*>(out_a + (size_t)nt * (VV * VV) + tid * 4) = av;
    }
    __syncthreads();
    const int f = tid;
    float h[VV];
    #pragma unroll
    for (int v = 0; v < VV; ++v) h[v] = 0.0f;
    #pragma unroll 4
    for (int c = 0; c < CC; ++c) {
        float wv = W[c * FF + f];
        #pragma unroll
        for (int v = 0; v < VV; ++v) h[v] = fmaf(x_lds[c][v], wv, h[v]);
    }
    const float bias = b[f];
    #pragma unroll
    for (int v = 0; v < VV; ++v) h[v] += bias;
    float o[VV];
    #pragma unroll
    for (int w = 0; w < VV; ++w) o[w] = 0.0f;
    #pragma unroll
    for (int v = 0; v < VV; ++v) {
        float hv = h[v];
        #pragma unroll
        for (int w = 0; w < VV; ++w) o[w] = fmaf(hv, a_lds[v][w], o[w]);
    }
    float* ob = out + (((size_t)n * FF + f) * TT + t) * VV;
    #pragma unroll
    for (int w = 0; w < VV; w += 4)
        *reinterpret_cast<float4*>(ob + w) = make_float4(o[w], o[w+1], o[w+2], o[w+3]);
}

extern "C" void kernel_launch(void* const* d_in, const int* in_sizes, int n_in,
                              void* d_out, int out_size, void* d_ws, size_t ws_size,
                              hipStream_t stream) {
    const float* x = (const float*)d_in[0];
    const float* a = (const float*)d_in[1];
    const float* W = (const float*)d_in[2];
    const float* b = (const float*)d_in[3];

    float* out   = (float*)d_out;
    float* out_a = out + (size_t)NN * FF * TT * VV;

    const size_t wt_bytes = (size_t)FF * CC * sizeof(_Float16);  // 131072

    if (ws_size >= wt_bytes) {
        _Float16* Wt = (_Float16*)d_ws;
        wt_prep_kernel<<<dim3(CC), dim3(FF), 0, stream>>>(W, Wt);
        sgcn_mfma4_kernel<<<dim3(NN * (TT / TB)), dim3(256), 0, stream>>>(x, a, Wt, b, out, out_a);
    } else {
        sgcn_fused_kernel<<<dim3(NN * TT), dim3(256), 0, stream>>>(x, a, W, b, out, out_a);
    }
}

// Round 8
// 210.559 us; speedup vs baseline: 1.2985x; 1.2985x over previous
//
#include <hip/hip_runtime.h>

// SGCN fused, MFMA v5: barrier-free wave-private pipeline.
// Each wave owns one t: GEMM-A (all 256 c, 4 chunks, x prefetch) -> private swizzled
// g in LDS (lgkmcnt-ordered, no barriers) -> GEMM-B (4 f-chunks, Wt from L2) -> stores.
// out[n,f,t,w] = sum_c W[c,f]*g[c,w] + b[f]*s[w],  g[c,w] = sum_v x[n,c,t,v]*a[n,t,v,w]
// x[128,256,64,32] f32, a[128,64,32,32] f32, W[256,256] f32, b[256] f32
// d_out = out (67,108,864 f32) ++ a (8,388,608 f32);  d_ws = Wt f16 [f][c] (131072 B)

#define NN 128
#define CC 256
#define TT 64
#define VV 32
#define FF 256
#define TB 4

typedef _Float16 half8 __attribute__((ext_vector_type(8)));
typedef _Float16 half4 __attribute__((ext_vector_type(4)));
typedef float floatx4 __attribute__((ext_vector_type(4)));

__global__ __launch_bounds__(256) void wt_prep_kernel(const float* __restrict__ W,
                                                      _Float16* __restrict__ Wt) {
    const int c = blockIdx.x;
    const int f = threadIdx.x;
    Wt[f * CC + c] = (_Float16)W[c * FF + f];
}

__global__ __launch_bounds__(256, 2) void sgcn_mfma5_kernel(
    const float* __restrict__ x, const float* __restrict__ a,
    const _Float16* __restrict__ Wt, const float* __restrict__ b,
    float* __restrict__ out, float* __restrict__ out_a)
{
    // a_t: rows (it*32+w) of 32 f16 v-values, 64B/row, swizzle byte ^= (row&3)<<4
    __shared__ _Float16 a_t[TB * VV * VV];          // 8 KB
    // g: per-wave private 32 rows (w) x 256 c f16, 512B/row, swizzle byte ^= (row&7)<<4
    __shared__ _Float16 g_s[4 * VV * 256];          // 64 KB
    __shared__ float    s_part[TB][4][VV];          // 2 KB
    // total ~74 KB -> 2 blocks/CU

    const int tid  = threadIdx.x;
    const int lane = tid & 63;
    const int wv   = tid >> 6;       // wave 0..3
    const int l15  = lane & 15;
    const int lg   = lane >> 4;      // 0..3
    const int blk  = blockIdx.x;
    const int n    = blk >> 4;       // TT/TB = 16 t-groups per n
    const int t0   = (blk & 15) * TB;
    const int t    = t0 + wv;        // this wave's t

    char* at_base = (char*)a_t;
    char* g_base  = (char*)g_s + wv * (VV * 256 * 2);   // private 16 KB

    // ---- prefetch x chunk 0 (c-tiles 0..3) for own t; in flight under a-staging
    float4 xf[8];
    #pragma unroll
    for (int ci = 0; ci < 4; ++ci) {
        const int c = ci * 16 + l15;
        const float* xp = x + (((size_t)n * CC + c) * TT + t) * VV + 8 * lg;
        xf[ci * 2 + 0] = *reinterpret_cast<const float4*>(xp);
        xf[ci * 2 + 1] = *reinterpret_cast<const float4*>(xp + 4);
    }

    // ---- stage a (TB t's): mirror to out tail, transposed f16 a_t, shfl partial sums
    {
        const int v  = tid >> 3;          // 0..31
        const int w0 = (tid & 7) * 4;     // 0,4,...,28
        #pragma unroll
        for (int it = 0; it < TB; ++it) {
            const size_t off = ((size_t)(n * TT + t0 + it)) * (VV * VV) + tid * 4;
            float4 av = *reinterpret_cast<const float4*>(a + off);
            *reinterpret_cast<float4*>(out_a + off) = av;
            #pragma unroll
            for (int j = 0; j < 4; ++j) {
                const int row = it * VV + w0 + j;
                const float e = j == 0 ? av.x : j == 1 ? av.y : j == 2 ? av.z : av.w;
                *reinterpret_cast<_Float16*>(at_base + row * 64 +
                                             ((v * 2) ^ ((row & 3) << 4))) = (_Float16)e;
            }
            float4 p = av;                 // partial col sums over this wave's 8 v's
            #pragma unroll
            for (int m = 8; m <= 32; m <<= 1) {
                p.x += __shfl_xor(p.x, m);
                p.y += __shfl_xor(p.y, m);
                p.z += __shfl_xor(p.z, m);
                p.w += __shfl_xor(p.w, m);
            }
            if ((lane >> 3) == 0)
                *reinterpret_cast<float4*>(&s_part[it][wv][w0]) = p;
        }
    }
    __syncthreads();                      // the ONLY barrier

    // ---- s[w] for own t, reduced by own wave, distributed to epilogue lanes
    float s_own = 0.0f;
    if (lane < VV) {
        #pragma unroll
        for (int q = 0; q < 4; ++q) s_own += s_part[wv][q][lane];
    }
    float sv[8];
    #pragma unroll
    for (int mt = 0; mt < 2; ++mt)
        #pragma unroll
        for (int j = 0; j < 4; ++j)
            sv[mt * 4 + j] = __shfl(s_own, 16 * mt + 4 * lg + j);

    // ---- bA frags for own t (one b128 each, swizzled rows)
    const int r0 = wv * VV + l15, r1 = r0 + 16;
    half8 bA0 = *reinterpret_cast<const half8*>(at_base + r0 * 64 +
                                                ((16 * lg) ^ ((r0 & 3) << 4)));
    half8 bA1 = *reinterpret_cast<const half8*>(at_base + r1 * 64 +
                                                ((16 * lg) ^ ((r1 & 3) << 4)));

    // ---- GEMM-A: all 256 c in 4 chunks; write private g (no barrier, lgkm-ordered)
    #pragma unroll
    for (int cc = 0; cc < 4; ++cc) {
        half8 af[4];
        #pragma unroll
        for (int ci = 0; ci < 4; ++ci) {
            float4 x0 = xf[ci * 2 + 0], x1 = xf[ci * 2 + 1];
            af[ci][0] = (_Float16)x0.x; af[ci][1] = (_Float16)x0.y;
            af[ci][2] = (_Float16)x0.z; af[ci][3] = (_Float16)x0.w;
            af[ci][4] = (_Float16)x1.x; af[ci][5] = (_Float16)x1.y;
            af[ci][6] = (_Float16)x1.z; af[ci][7] = (_Float16)x1.w;
        }
        if (cc < 3) {                      // prefetch next chunk
            #pragma unroll
            for (int ci = 0; ci < 4; ++ci) {
                const int c = ((cc + 1) * 4 + ci) * 16 + l15;
                const float* xp = x + (((size_t)n * CC + c) * TT + t) * VV + 8 * lg;
                xf[ci * 2 + 0] = *reinterpret_cast<const float4*>(xp);
                xf[ci * 2 + 1] = *reinterpret_cast<const float4*>(xp + 4);
            }
        }
        #pragma unroll
        for (int ci = 0; ci < 4; ++ci) {
            const int ct = cc * 4 + ci;
            #pragma unroll
            for (int wt = 0; wt < 2; ++wt) {
                floatx4 acc = {0.f, 0.f, 0.f, 0.f};
                acc = __builtin_amdgcn_mfma_f32_16x16x32_f16(af[ci], wt ? bA1 : bA0, acc, 0, 0, 0);
                half4 gh;
                gh[0] = (_Float16)acc[0]; gh[1] = (_Float16)acc[1];
                gh[2] = (_Float16)acc[2]; gh[3] = (_Float16)acc[3];
                const int row = 16 * wt + l15;
                const int cb  = (ct * 16 + 4 * lg) * 2;
                *reinterpret_cast<half4*>(g_base + row * 512 + (cb ^ ((row & 7) << 4))) = gh;
            }
        }
    }

    // ---- GEMM-B: D[w,f] = g^T · Wt in 4 f-chunks (acc stays at 8 x floatx4)
    #pragma unroll
    for (int fc = 0; fc < 4; ++fc) {
        float bvf[4];
        #pragma unroll
        for (int fi = 0; fi < 4; ++fi) bvf[fi] = b[fc * 64 + fi * 16 + l15];

        floatx4 acc2[8];
        #pragma unroll
        for (int q = 0; q < 8; ++q) acc2[q] = (floatx4){0.f, 0.f, 0.f, 0.f};

        __builtin_amdgcn_s_setprio(1);
        #pragma unroll
        for (int ks = 0; ks < 8; ++ks) {
            const int cb = (32 * ks + 8 * lg) * 2;
            half8 ga0 = *reinterpret_cast<const half8*>(g_base + l15 * 512 +
                                                        (cb ^ ((l15 & 7) << 4)));
            half8 ga1 = *reinterpret_cast<const half8*>(g_base + (16 + l15) * 512 +
                                                        (cb ^ (((16 + l15) & 7) << 4)));
            #pragma unroll
            for (int fi = 0; fi < 4; ++fi) {
                const int f = fc * 64 + fi * 16 + l15;
                half8 wb = *reinterpret_cast<const half8*>(Wt + (size_t)f * CC + 32 * ks + 8 * lg);
                acc2[fi * 2 + 0] = __builtin_amdgcn_mfma_f32_16x16x32_f16(ga0, wb, acc2[fi * 2 + 0], 0, 0, 0);
                acc2[fi * 2 + 1] = __builtin_amdgcn_mfma_f32_16x16x32_f16(ga1, wb, acc2[fi * 2 + 1], 0, 0, 0);
            }
        }
        __builtin_amdgcn_s_setprio(0);

        // epilogue for this f-chunk (stores overlap next chunk's loads)
        #pragma unroll
        for (int fi = 0; fi < 4; ++fi) {
            const int f = fc * 64 + fi * 16 + l15;
            float* ob = out + (((size_t)n * FF + f) * TT + t) * VV;
            #pragma unroll
            for (int mt = 0; mt < 2; ++mt) {
                const int w0 = 16 * mt + 4 * lg;
                float4 o;
                o.x = acc2[fi * 2 + mt][0] + bvf[fi] * sv[mt * 4 + 0];
                o.y = acc2[fi * 2 + mt][1] + bvf[fi] * sv[mt * 4 + 1];
                o.z = acc2[fi * 2 + mt][2] + bvf[fi] * sv[mt * 4 + 2];
                o.w = acc2[fi * 2 + mt][3] + bvf[fi] * sv[mt * 4 + 3];
                *reinterpret_cast<float4*>(ob + w0) = o;
            }
        }
    }
}

// ---- fallback (verified round-3 scalar kernel): used only if ws too small
__global__ __launch_bounds__(256) void sgcn_fused_kernel(
    const float* __restrict__ x, const float* __restrict__ a,
    const float* __restrict__ W, const float* __restrict__ b,
    float* __restrict__ out, float* __restrict__ out_a)
{
    __shared__ float x_lds[CC][VV];
    __shared__ float a_lds[VV][VV];
    const int tid = threadIdx.x;
    const int nt  = blockIdx.x;
    const int n   = nt >> 6;
    const int t   = nt & 63;
    const float* xb = x + (size_t)n * CC * TT * VV + (size_t)t * VV;
    #pragma unroll
    for (int k = 0; k < 8; ++k) {
        int e = tid * 4 + k * 1024;
        int c = e >> 5, v = e & 31;
        float4 val = *reinterpret_cast<const float4*>(xb + (size_t)c * (TT * VV) + v);
        *reinterpret_cast<float4*>(&x_lds[c][v]) = val;
    }
    {
        const float* ab = a + (size_t)nt * (VV * VV);
        float4 av = *reinterpret_cast<const float4*>(ab + tid * 4);
        *reinterpret_cast<float4*>(&a_lds[0][0] + tid * 4) = av;
        *reinterpret_cast<float4*>(out_a + (size_t)nt * (VV * VV) + tid * 4) = av;
    }
    __syncthreads();
    const int f = tid;
    float h[VV];
    #pragma unroll
    for (int v = 0; v < VV; ++v) h[v] = 0.0f;
    #pragma unroll 4
    for (int c = 0; c < CC; ++c) {
        float wv = W[c * FF + f];
        #pragma unroll
        for (int v = 0; v < VV; ++v) h[v] = fmaf(x_lds[c][v], wv, h[v]);
    }
    const float bias = b[f];
    #pragma unroll
    for (int v = 0; v < VV; ++v) h[v] += bias;
    float o[VV];
    #pragma unroll
    for (int w = 0; w < VV; ++w) o[w] = 0.0f;
    #pragma unroll
    for (int v = 0; v < VV; ++v) {
        float hv = h[v];
        #pragma unroll
        for (int w = 0; w < VV; ++w) o[w] = fmaf(hv, a_lds[v][w], o[w]);
    }
    float* ob = out + (((size_t)n * FF + f) * TT + t) * VV;
    #pragma unroll
    for (int w = 0; w < VV; w += 4)
        *reinterpret_cast<float4*>(ob + w) = make_float4(o[w], o[w+1], o[w+2], o[w+3]);
}

extern "C" void kernel_launch(void* const* d_in, const int* in_sizes, int n_in,
                              void* d_out, int out_size, void* d_ws, size_t ws_size,
                              hipStream_t stream) {
    const float* x = (const float*)d_in[0];
    const float* a = (const float*)d_in[1];
    const float* W = (const float*)d_in[2];
    const float* b = (const float*)d_in[3];

    float* out   = (float*)d_out;
    float* out_a = out + (size_t)NN * FF * TT * VV;

    const size_t wt_bytes = (size_t)FF * CC * sizeof(_Float16);  // 131072

    if (ws_size >= wt_bytes) {
        _Float16* Wt = (_Float16*)d_ws;
        wt_prep_kernel<<<dim3(CC), dim3(FF), 0, stream>>>(W, Wt);
        sgcn_mfma5_kernel<<<dim3(NN * (TT / TB)), dim3(256), 0, stream>>>(x, a, Wt, b, out, out_a);
    } else {
        sgcn_fused_kernel<<<dim3(NN * TT), dim3(256), 0, stream>>>(x, a, W, b, out, out_a);
    }
}